// Round 2
// baseline (14454.832 us; speedup 1.0000x reference)
//
#include <hip/hip_runtime.h>
#include <stdint.h>

// ============================================================================
// RecurrentAutoEncoder (2-layer LSTM enc + 2-layer LSTM dec + FC).
// ALL inputs/outputs are FP32 (per reference). Internally: bf16 MFMA
// fragments, fp32 accum.
//   Phase A (coop, 256 WGs): enc0 --ring(4)--> enc1  (enc1 seq discarded)
//   Phase B (coop, 256 WGs): dec0 --ring(4)--> dec1 --(delay 4)--> fused FC
// h buffers: 8-plane bf16 rings; enc->dec h_T handoff free (512 % 8 == 0).
//
// v2 (prev): per-WG flag words + relaxed agent (sc0 sc1) loads/stores killed
// the RMW/wbl2 storm: 24 -> 13.6 us/step. Remaining cost: every ring load
// bypasses L2 -> ~28 MB/step of same-line x64 multicast IF$ traffic inflates
// every coherent round trip on the critical path.
//
// v3 (this round): cache ring data in L2, invalidate once per step.
//   * ring loads (h-ring, x-ring, FC input) = inline-asm global_load sc0
//     (bypass L1 only, CACHE in L2). Staleness hazard = ring reuse 8 steps
//     ago; killed by a per-wave agent ACQUIRE (emits s_waitcnt + buffer_inv
//     sc1) issued right after the flag poll succeeds, before the loads.
//   * asm loads are raw: explicit s_waitcnt vmcnt(0) + sched_barrier(0)
//     before the MFMAs that consume them (rule: compiler can hoist reg-only
//     MFMA past inline-asm waitcnt).
//   * buffer_inv may discard dirty L2 lines -> ALL global stores that must
//     survive are write-through agent stores: h-rings (already), FC out (new).
//   * flag polls stay on the bypass path (sc0 sc1) -- flags must never be
//     served from a stale L2 line.
// d_ws footprint unchanged: 3.1 MiB.
// ============================================================================

using bf16x8 = __attribute__((ext_vector_type(8))) short;   // 8 bf16 = 4 VGPR
using f32x16 = __attribute__((ext_vector_type(16))) float;  // 32x32 mfma acc
using f32x4  = __attribute__((ext_vector_type(4))) float;   // 16x16 mfma acc

#define MFMA32(a, b, c) __builtin_amdgcn_mfma_f32_32x32x16_bf16((a), (b), (c), 0, 0, 0)
#define MFMA16(a, b, c) __builtin_amdgcn_mfma_f32_16x16x32_bf16((a), (b), (c), 0, 0, 0)

static __device__ __forceinline__ uint16_t f2bf(float f) {
  union { float f; uint32_t u; } v; v.f = f;
  uint32_t u = v.u;
  return (uint16_t)((u + 0x7fffu + ((u >> 16) & 1u)) >> 16);  // RNE
}
static __device__ __forceinline__ float sigm(float x) { return 1.0f / (1.0f + __expf(-x)); }
static __device__ __forceinline__ float tanh_f(float x) { return 2.0f / (1.0f + __expf(-2.0f * x)) - 1.0f; }

static __device__ __forceinline__ bf16x8 cvt8(const float* p) {
  bf16x8 r;
#pragma unroll
  for (int i = 0; i < 8; ++i) { uint16_t b = f2bf(p[i]); r[i] = (short)b; }
  return r;
}

// ---- sync/data helpers ----
// flag loads: full bypass (sc0 sc1) -- must always see fresh IF$ state.
static __device__ __forceinline__ uint32_t aldf(const uint32_t* p) {
  return __hip_atomic_load(p, __ATOMIC_RELAXED, __HIP_MEMORY_SCOPE_AGENT);
}
// ring data loads: sc0 only -> bypass L1, CACHE in L2 (shared per XCD).
// Raw asm: caller must s_waitcnt vmcnt(0) + sched_barrier(0) before use.
static __device__ __forceinline__ void ldg_sc0(bf16x8& d, const uint16_t* p) {
  asm volatile("global_load_dwordx4 %0, %1, off sc0" : "=v"(d) : "v"(p) : "memory");
}
// write-through agent store (survives buffer_inv; visible at IF$)
static __device__ __forceinline__ void ast32(uint16_t* p, uint32_t v) {
  __hip_atomic_store((uint32_t*)p, v, __ATOMIC_RELAXED, __HIP_MEMORY_SCOPE_AGENT);
}
static __device__ __forceinline__ void astf(float* p, float v) {
  __hip_atomic_store(p, v, __ATOMIC_RELAXED, __HIP_MEMORY_SCOPE_AGENT);
}

// ---------------- workspace layout (bytes); total 3,146,752 B ----------------
static const size_t OFF_FLG = 0;                  // [4][64] u32 per-WG step flags
static const size_t OFF_HB0 = 1024;               // [8][128][512] bf16 h-ring (enc0/dec0)
static const size_t OFF_HB1 = 1024 + 1048576;     // [8][128][512] bf16 h-ring (enc1/dec1)
static const size_t OFF_E0R = 1024 + 2097152;     // [4][128][512] bf16 ring enc0->enc1
static const size_t OFF_D0R = 1024 + 2621440;     // [4][128][512] bf16 ring dec0->dec1

// ---------------- init: zero flags + h-ring plane0 (h_{-1}=0) ------------
__global__ void init_kernel(uint32_t* flg, uint32_t* h0a, uint32_t* h0b) {
  int i = (int)blockIdx.x * 256 + (int)threadIdx.x;
  if (i < 256) flg[i] = 0;
  for (int j = i; j < 32768; j += (int)gridDim.x * 256) { h0a[j] = 0; h0b[j] = 0; }
}

// ---------------- pipelined persistent LSTM layer kernel ----------------
struct PJob {
  const float* whh;       // [2048][512] fp32
  const float* wih;       // [2048][KX] fp32
  const float* bih;       // [2048] fp32
  const float* bhh;       // [2048] fp32
  const float* xf;        // fp32 x [128][512][KX] (enc0/dec0) or null
  const uint16_t* xring;  // [4][128][512] bf16 ring (enc1/dec1) or null
  uint16_t* hring;        // [8][128][512] bf16; plane0 = h_{-1}
  const float* c0;        // [128][512] fp32 or null (zeros)
  uint16_t* ringout;      // [4][128][512] bf16 or null
  uint32_t* fown;         // [2][64] own per-WG flags (per batch-group)
  const uint32_t* fprod;  // [2][64] producer flags or null (ring input ready)
  const uint32_t* fcons;  // [2][64] consumer flags or null (ring free / FC src)
  const float* fcw;       // [128][512] fp32 or null (dec0 only)
  const float* fcb;       // [128] fp32
  const uint16_t* fchr;   // dec1 h-ring (FC input)
  float* out;             // d_out [128][512][128] fp32
  int KX;                 // 128 or 512
  int shift;              // 1 for dec0 (input = x shifted right one step)
  int tsteps;             // 512, or 516 for dec0 (FC drain tail)
  uint32_t fb;            // flag base: 0 (phase A) or 512 (phase B)
};

__global__ void __launch_bounds__(256, 1) lstm_pipe(PJob j0, PJob j1) {
  const PJob J = ((int)blockIdx.x < 128) ? j0 : j1;
  const int lb = (int)blockIdx.x & 127;
  const int bg = lb >> 6, u = lb & 63, b0 = bg * 64;
  const int tid = (int)threadIdx.x;
  const int wv = tid >> 6, ln = tid & 63;

  __shared__ __align__(16) uint16_t Wl[40960];  // 64K rec weights + 16K fcW (80 KiB)
  __shared__ float gb[2][64][33];               // k-partial gates (+1 pad)
  __shared__ float cst[64][9];                  // fp32 cell state (+1 pad)

  const int KX = J.KX;
  const int NTX = KX >> 5;          // x k-blocks per k-half (4 or 16)
  const int HS = (16 + NTX) * 512;  // packed elems per k-half

  // ---- gather [Whh ; Wih] chunk u from global fp32 -> LDS bf16 MFMA-B frags
  {
    const int nfrag = (2 * HS) >> 3;
    for (int f = tid; f < nfrag; f += 256) {
      int lane = f & 63;
      int kt2 = f >> 6;                       // kh*(16+NTX) + kt
      int kh = (kt2 >= 16 + NTX) ? 1 : 0;
      int kt = kt2 - kh * (16 + NTX);
      int col = lane & 31;
      int wrow = ((col >> 3) << 9) + (u << 3) + (col & 7);
      int m = (kt << 4) + ((lane >> 5) << 3);
      const float* src = (m < 256)
          ? J.whh + (size_t)wrow * 512 + (kh << 8) + m
          : J.wih + (size_t)wrow * KX + kh * (KX >> 1) + (m - 256);
      union { uint16_t h[8]; ulonglong2 v; } tmp;
#pragma unroll
      for (int j = 0; j < 8; ++j) tmp.h[j] = f2bf(src[j]);
      *(ulonglong2*)(Wl + (size_t)f * 8) = tmp.v;
    }
  }

  // FC assignment: dec0 WGs with u<8; wave wv owns out tile (ftr, ftc)
  const int isfc = (J.fcw != nullptr) && (u < 8);
  const int wgti = bg * 8 + u;             // 0..15
  const int ftc = wgti & 7;
  const int ftr = 2 * wv + (wgti >> 3);    // 0..7
  const int fcol = ftc * 16 + (ln & 15);
  const int farow = ftr * 16 + (ln & 15);
  float fbv = 0.0f;
  if (isfc) {
    fbv = J.fcb[fcol];
    for (int f = tid; f < 1024; f += 256) {
      int lane = f & 63, kt = f >> 6;
      int row = ftc * 16 + (lane & 15);
      int k = (kt << 5) + ((lane >> 4) << 3);
      const float* src = J.fcw + (size_t)row * 512 + k;
      union { uint16_t h[8]; ulonglong2 v; } tmp;
#pragma unroll
      for (int j = 0; j < 8; ++j) tmp.h[j] = f2bf(src[j]);
      *(ulonglong2*)(Wl + 32768 + (size_t)f * 8) = tmp.v;
    }
  }

  // ---- per-thread epilogue assignment: 2 hidden units ----
  const int rl = tid >> 2, ul2 = (tid & 3) * 2, bE = b0 + rl;
  const int hu = u * 8 + ul2;  // original hidden-unit index (pair base)
  const float Bi0 = J.bih[hu] + J.bhh[hu];
  const float Bi1 = J.bih[hu + 1] + J.bhh[hu + 1];
  const float Bf0 = J.bih[512 + hu] + J.bhh[512 + hu];
  const float Bf1 = J.bih[513 + hu] + J.bhh[513 + hu];
  const float Bg0 = J.bih[1024 + hu] + J.bhh[1024 + hu];
  const float Bg1 = J.bih[1025 + hu] + J.bhh[1025 + hu];
  const float Bo0 = J.bih[1536 + hu] + J.bhh[1536 + hu];
  const float Bo1 = J.bih[1537 + hu] + J.bhh[1537 + hu];
  {
    float c0v = 0.f, c1v = 0.f;
    if (J.c0) {
      c0v = J.c0[(size_t)bE * 512 + hu];
      c1v = J.c0[(size_t)bE * 512 + hu + 1];
    }
    cst[rl][ul2] = c0v;
    cst[rl][ul2 + 1] = c1v;
  }
  __syncthreads();

  const int mt = wv & 1, kh = wv >> 1;
  const int arow = b0 + mt * 32 + (ln & 31);
  const size_t hbase = (size_t)arow * 512 + (size_t)kh * 256 + ((ln >> 5) << 3);
  const uint16_t* wlh = Wl + (size_t)kh * HS + (size_t)ln * 8;
  const uint16_t* wlx = wlh + 16 * 512;
  const size_t hwr = (size_t)bE * 512 + hu;
  const int tsteps = J.tsteps;
  const uint32_t FB = J.fb;

  for (int t = 0; t < tsteps; ++t) {
    f32x16 acc;
#pragma unroll
    for (int r = 0; r < 16; ++r) acc[r] = 0.0f;

    // ---- x-part from global fp32 (enc0/dec0): no cross-WG dep -> pre-wait
    if (t < 512 && J.xring == nullptr) {
      const int tx = t - J.shift;
      if (tx >= 0) {
        const float* xb = J.xf + (size_t)arow * (512 * (size_t)KX) +
                          (size_t)tx * KX + kh * (KX >> 1) + ((ln >> 5) << 3);
        for (int kt = 0; kt < NTX; ++kt) {
          bf16x8 af = cvt8(xb + kt * 16);
          acc = MFMA32(af, *(const bf16x8*)(wlx + kt * 512), acc);
        }
      }
    }

    // ---- cross-WG flag waits: wave 0, one flag per lane, parallel poll ----
    if (wv == 0) {
      const uint32_t* po = J.fown + bg * 64;
      const uint32_t* pp = J.fprod ? J.fprod + bg * 64 : nullptr;
      const uint32_t* pc = J.fcons ? J.fcons + bg * 64 : nullptr;
      const uint32_t* pf = isfc ? J.fcons + (1 - bg) * 64 : nullptr;
      const int w_own = (t > 0) && (t <= 512);
      const int w_prod = (pp != nullptr) && (t < 512);
      const int w_cons = (pc != nullptr) && (t >= 4) && ((t < 512) || isfc);
      const int w_fc = (pf != nullptr) && (t >= 4);
      if (w_own || w_prod || w_cons || w_fc) {
        const uint32_t to = FB + (uint32_t)t;
        const uint32_t tp = to + 1u;
        const uint32_t tc = to - 3u;
        while (1) {
          int ok = 1;
          if (w_own)  ok &= (aldf(po + ln) >= to);
          if (w_prod) ok &= (aldf(pp + ln) >= tp);
          if (w_cons) ok &= (aldf(pc + ln) >= tc);
          if (w_fc)   ok &= (aldf(pf + ln) >= tc);
          if (__all(ok)) break;
          __builtin_amdgcn_s_sleep(1);
        }
      }
    }
    __syncthreads();

    // ---- per-wave agent ACQUIRE: emits s_waitcnt + buffer_inv sc1 so the
    // sc0 ring loads below cannot hit stale L2 lines (ring reuse 8 steps
    // ago, or previous phase/iteration). One inv per wave per step.
    if ((t < 512) || (isfc && t >= 4)) {
      if (ln == 0)
        (void)__hip_atomic_load(J.fown + bg * 64 + u, __ATOMIC_ACQUIRE,
                                __HIP_MEMORY_SCOPE_AGENT);
    }

    if (t < 512) {
      // h-part: K 256 per half, from 8-plane bf16 ring via L2-cached sc0
      // loads (raw asm: explicit waitcnt + sched fence before the MFMAs).
      const uint16_t* hb = J.hring + (size_t)(t & 7) * 65536 + hbase;
      bf16x8 ah[16];
#pragma unroll
      for (int kt = 0; kt < 16; ++kt) ldg_sc0(ah[kt], hb + kt * 16);
      if (J.xring) {  // previous layer's h ring (bf16, 512 wide)
        const uint16_t* xb = J.xring + (size_t)(t & 3) * 65536 + hbase;
        bf16x8 ax[16];
#pragma unroll
        for (int kt = 0; kt < 16; ++kt) ldg_sc0(ax[kt], xb + kt * 16);
        asm volatile("s_waitcnt vmcnt(0)" ::: "memory");
        __builtin_amdgcn_sched_barrier(0);
#pragma unroll
        for (int kt = 0; kt < 16; ++kt)
          acc = MFMA32(ah[kt], *(const bf16x8*)(wlh + kt * 512), acc);
#pragma unroll
        for (int kt = 0; kt < 16; ++kt)
          acc = MFMA32(ax[kt], *(const bf16x8*)(wlx + kt * 512), acc);
      } else {
        asm volatile("s_waitcnt vmcnt(0)" ::: "memory");
        __builtin_amdgcn_sched_barrier(0);
#pragma unroll
        for (int kt = 0; kt < 16; ++kt)
          acc = MFMA32(ah[kt], *(const bf16x8*)(wlh + kt * 512), acc);
      }
#pragma unroll
      for (int r = 0; r < 16; ++r) {
        int crow = (r & 3) + 8 * (r >> 2) + 4 * (ln >> 5);
        gb[kh][mt * 32 + crow][ln & 31] = acc[r];
      }
      __syncthreads();

      // ---- epilogue: 2 hidden units per thread ----
      float i0 = sigm(gb[0][rl][ul2]      + gb[1][rl][ul2]      + Bi0);
      float i1 = sigm(gb[0][rl][ul2 + 1]  + gb[1][rl][ul2 + 1]  + Bi1);
      float f0 = sigm(gb[0][rl][8 + ul2]  + gb[1][rl][8 + ul2]  + Bf0);
      float f1 = sigm(gb[0][rl][9 + ul2]  + gb[1][rl][9 + ul2]  + Bf1);
      float g0 = tanh_f(gb[0][rl][16 + ul2] + gb[1][rl][16 + ul2] + Bg0);
      float g1 = tanh_f(gb[0][rl][17 + ul2] + gb[1][rl][17 + ul2] + Bg1);
      float o0 = sigm(gb[0][rl][24 + ul2] + gb[1][rl][24 + ul2] + Bo0);
      float o1 = sigm(gb[0][rl][25 + ul2] + gb[1][rl][25 + ul2] + Bo1);
      float cc0 = f0 * cst[rl][ul2]     + i0 * g0;
      float cc1 = f1 * cst[rl][ul2 + 1] + i1 * g1;
      cst[rl][ul2] = cc0;
      cst[rl][ul2 + 1] = cc1;
      float h0 = o0 * tanh_f(cc0);
      float h1 = o1 * tanh_f(cc1);
      uint32_t hv = (uint32_t)f2bf(h0) | ((uint32_t)f2bf(h1) << 16);
      // write-through device stores (survive buffer_inv, land at IF$)
      ast32(J.hring + (size_t)((t + 1) & 7) * 65536 + hwr, hv);
      if (J.ringout)
        ast32(J.ringout + (size_t)(t & 3) * 65536 + hwr, hv);

      // barrier drains every wave's vmcnt -> all stores device-visible
      __syncthreads();
      if (tid == 0) {
        asm volatile("s_waitcnt vmcnt(0)" ::: "memory");
        __hip_atomic_store(J.fown + bg * 64 + u, FB + (uint32_t)(t + 1),
                           __ATOMIC_RELAXED, __HIP_MEMORY_SCOPE_AGENT);
      }
    }

    // ---- fused FC head: out[:, t-4] = dec1_h(t-4) @ fcW^T + fcb (fp32) ----
    if (isfc && t >= 4) {
      const int tf = t - 4;
      const uint16_t* ha = J.fchr + (size_t)((tf + 1) & 7) * 65536 +
                           (size_t)farow * 512 + ((ln >> 4) << 3);
      const uint16_t* wb = Wl + 32768 + (size_t)ln * 8;
      bf16x8 af[16];
#pragma unroll
      for (int kt = 0; kt < 16; ++kt) ldg_sc0(af[kt], ha + kt * 32);
      asm volatile("s_waitcnt vmcnt(0)" ::: "memory");
      __builtin_amdgcn_sched_barrier(0);
      f32x4 fa;
      fa[0] = fa[1] = fa[2] = fa[3] = 0.0f;
#pragma unroll
      for (int kt = 0; kt < 16; ++kt)
        fa = MFMA16(af[kt], *(const bf16x8*)(wb + kt * 512), fa);
#pragma unroll
      for (int r = 0; r < 4; ++r) {
        int row = ftr * 16 + ((ln >> 4) << 2) + r;  // batch index
        astf(&J.out[((size_t)row * 512 + tf) * 128 + fcol], fa[r] + fbv);
      }
    }
  }
}

// ---------------- host launch ----------------
extern "C" void kernel_launch(void* const* d_in, const int* in_sizes, int n_in,
                              void* d_out, int out_size, void* d_ws, size_t ws_size,
                              hipStream_t stream) {
  (void)in_sizes; (void)n_in; (void)out_size; (void)ws_size;
  uint8_t* ws = (uint8_t*)d_ws;
  const float* x     = (const float*)d_in[0];
  const float* c_dec = (const float*)d_in[1];
  const float* W[16];
  for (int i = 0; i < 16; ++i) W[i] = (const float*)d_in[2 + i];
  // layer order in d_in: enc0{wih,whh,bih,bhh} enc1{...} dec0{...} dec1{...}
  const float* fcW = (const float*)d_in[18];
  const float* fcb = (const float*)d_in[19];

  uint32_t* FLG = (uint32_t*)(ws + OFF_FLG);
  uint16_t* HB0 = (uint16_t*)(ws + OFF_HB0);
  uint16_t* HB1 = (uint16_t*)(ws + OFF_HB1);
  uint16_t* E0R = (uint16_t*)(ws + OFF_E0R);
  uint16_t* D0R = (uint16_t*)(ws + OFF_D0R);
  // flag arrays: [2][64] for layer0 (enc0/dec0), [2][64] for layer1
  uint32_t* FL0 = FLG + 0;    // L0: bg0 [0..63], bg1 [64..127]
  uint32_t* FL1 = FLG + 128;  // L1: bg0 [0..63], bg1 [64..127]

  // 1) zero flags + h-ring plane0 (h_{-1} = 0)
  hipLaunchKernelGGL(init_kernel, dim3(128), dim3(256), 0, stream,
                     FLG, (uint32_t*)HB0, (uint32_t*)HB1);

  // 2) phase A: enc0 (x -> E0R, h in HB0) || enc1 (E0R -> HB1; seq discarded)
  {
    PJob a; a.whh = W[1]; a.wih = W[0]; a.bih = W[2]; a.bhh = W[3];
    a.xf = x; a.xring = nullptr; a.hring = HB0; a.c0 = nullptr; a.ringout = E0R;
    a.fown = FL0; a.fprod = nullptr; a.fcons = FL1;
    a.fcw = nullptr; a.fcb = nullptr; a.fchr = nullptr; a.out = nullptr;
    a.KX = 128; a.shift = 0; a.tsteps = 512; a.fb = 0;
    PJob b; b.whh = W[5]; b.wih = W[4]; b.bih = W[6]; b.bhh = W[7];
    b.xf = nullptr; b.xring = E0R; b.hring = HB1; b.c0 = nullptr; b.ringout = nullptr;
    b.fown = FL1; b.fprod = FL0; b.fcons = nullptr;
    b.fcw = nullptr; b.fcb = nullptr; b.fchr = nullptr; b.out = nullptr;
    b.KX = 512; b.shift = 0; b.tsteps = 512; b.fb = 0;
    void* args[2] = { &a, &b };
    hipLaunchCooperativeKernel((const void*)lstm_pipe, dim3(256), dim3(256), args, 0, stream);
  }

  // 3) phase B: dec0 (shift(x) -> D0R, h0 = enc0 hT in HB0 plane0, c0=c_dec[0],
  //    + fused FC from dec1's ring) || dec1 (D0R -> HB1, h0 = enc1 hT, c0=c_dec[1])
  //    Flag arrays reused with fb=512 (phase A leaves every flag at exactly 512).
  {
    PJob a; a.whh = W[9]; a.wih = W[8]; a.bih = W[10]; a.bhh = W[11];
    a.xf = x; a.xring = nullptr; a.hring = HB0; a.c0 = c_dec; a.ringout = D0R;
    a.fown = FL0; a.fprod = nullptr; a.fcons = FL1;
    a.fcw = fcW; a.fcb = fcb; a.fchr = HB1; a.out = (float*)d_out;
    a.KX = 128; a.shift = 1; a.tsteps = 516; a.fb = 512;
    PJob b; b.whh = W[13]; b.wih = W[12]; b.bih = W[14]; b.bhh = W[15];
    b.xf = nullptr; b.xring = D0R; b.hring = HB1; b.c0 = c_dec + 65536; b.ringout = nullptr;
    b.fown = FL1; b.fprod = FL0; b.fcons = nullptr;
    b.fcw = nullptr; b.fcb = nullptr; b.fchr = nullptr; b.out = nullptr;
    b.KX = 512; b.shift = 0; b.tsteps = 512; b.fb = 512;
    void* args[2] = { &a, &b };
    hipLaunchCooperativeKernel((const void*)lstm_pipe, dim3(256), dim3(256), args, 0, stream);
  }
}

// Round 4
// 8697.111 us; speedup vs baseline: 1.6620x; 1.6620x over previous
//
#include <hip/hip_runtime.h>
#include <stdint.h>

// ============================================================================
// RecurrentAutoEncoder (2-layer LSTM enc + 2-layer LSTM dec + FC).
// ALL inputs/outputs are FP32 (per reference). Internally: bf16 MFMA
// fragments, fp32 accum.
//   Phase A (coop, 256 WGs): enc0 --hring--> enc1  (enc1 seq discarded)
//   Phase B (coop, 256 WGs): dec0 --hring--> dec1 --(delay 4)--> fused FC
// h buffers: 8-plane bf16 rings; enc->dec h_T handoff free (512 % 8 == 0).
//
// v2: per-WG flag words + relaxed agent (sc0 sc1) loads/stores (no RMW, no
//     wbl2/inv): 24 -> 13.6 us/step.
// v3 (REFUTED): L2-caching ring data + per-wave buffer_inv regressed 10%
//     (the inv storm wiped x/weights too) + a 58ms cold-start outlier.
// v4 (this round, resubmit -- r3 was a compile error in the store-asm
//     constraint: ulonglong2 is a struct; must use ext_vector_type):
//   attack fabric TRANSACTION COUNT on the critical path:
//   * LDS-gathered h-store: epilogue stages h-slice in LDS; wave0 alone
//     issues 64 x 16B sc0sc1 stores + vmcnt(0) + flag. Was 256 x 4B stores
//     from 4 waves (+256 more for ringout) all draining before the flag.
//   * ringout ELIMINATED: layer1 reads the producer's own 8-plane h-ring at
//     plane (t+1)&7. Consumer-throttle slack 4 -> 7 (8-plane ring; safety
//     from per-WG iteration sequentiality).
//   * consumer fragment loads: 16B asm global_load_dwordx4 sc0 sc1 (was
//     2 x 8B atomic loads) + single vmcnt(0) + sched_barrier(0) (rule #18).
// d_ws footprint: 2.1 MiB.
// ============================================================================

using bf16x8 = __attribute__((ext_vector_type(8))) short;   // 8 bf16 = 4 VGPR
using u32x4  = __attribute__((ext_vector_type(4))) uint32_t; // 4 VGPR payload
using f32x16 = __attribute__((ext_vector_type(16))) float;  // 32x32 mfma acc
using f32x4  = __attribute__((ext_vector_type(4))) float;   // 16x16 mfma acc

#define MFMA32(a, b, c) __builtin_amdgcn_mfma_f32_32x32x16_bf16((a), (b), (c), 0, 0, 0)
#define MFMA16(a, b, c) __builtin_amdgcn_mfma_f32_16x16x32_bf16((a), (b), (c), 0, 0, 0)

static __device__ __forceinline__ uint16_t f2bf(float f) {
  union { float f; uint32_t u; } v; v.f = f;
  uint32_t u = v.u;
  return (uint16_t)((u + 0x7fffu + ((u >> 16) & 1u)) >> 16);  // RNE
}
static __device__ __forceinline__ float sigm(float x) { return 1.0f / (1.0f + __expf(-x)); }
static __device__ __forceinline__ float tanh_f(float x) { return 2.0f / (1.0f + __expf(-2.0f * x)) - 1.0f; }

static __device__ __forceinline__ bf16x8 cvt8(const float* p) {
  bf16x8 r;
#pragma unroll
  for (int i = 0; i < 8; ++i) { uint16_t b = f2bf(p[i]); r[i] = (short)b; }
  return r;
}

// ---- sync/data helpers (all device-coherent, no cache-maintenance ops) ----
static __device__ __forceinline__ uint32_t aldf(const uint32_t* p) {
  return __hip_atomic_load(p, __ATOMIC_RELAXED, __HIP_MEMORY_SCOPE_AGENT);
}
// 16B coherent load, raw asm: caller must s_waitcnt vmcnt(0)+sched_barrier(0)
static __device__ __forceinline__ void ldg16(bf16x8& d, const uint16_t* p) {
  asm volatile("global_load_dwordx4 %0, %1, off sc0 sc1" : "=v"(d) : "v"(p) : "memory");
}
// 16B coherent write-through store (payload must be ext_vector_type for "v")
static __device__ __forceinline__ void stg16(uint16_t* p, u32x4 v) {
  asm volatile("global_store_dwordx4 %0, %1, off sc0 sc1" :: "v"(p), "v"(v) : "memory");
}

// ---------------- workspace layout (bytes); total 2,098,176 B ----------------
static const size_t OFF_FLG = 0;                  // [4][64] u32 per-WG step flags
static const size_t OFF_HB0 = 1024;               // [8][128][512] bf16 h-ring (enc0/dec0)
static const size_t OFF_HB1 = 1024 + 1048576;     // [8][128][512] bf16 h-ring (enc1/dec1)

// ---------------- init: zero flags + h-ring plane0 (h_{-1}=0) ------------
__global__ void init_kernel(uint32_t* flg, uint32_t* h0a, uint32_t* h0b) {
  int i = (int)blockIdx.x * 256 + (int)threadIdx.x;
  if (i < 256) flg[i] = 0;
  for (int j = i; j < 32768; j += (int)gridDim.x * 256) { h0a[j] = 0; h0b[j] = 0; }
}

// ---------------- pipelined persistent LSTM layer kernel ----------------
struct PJob {
  const float* whh;       // [2048][512] fp32
  const float* wih;       // [2048][KX] fp32
  const float* bih;       // [2048] fp32
  const float* bhh;       // [2048] fp32
  const float* xf;        // fp32 x [128][512][KX] (enc0/dec0) or null
  const uint16_t* xring;  // producer's 8-plane h-ring (enc1/dec1) or null
  uint16_t* hring;        // [8][128][512] bf16; plane0 = h_{-1}
  const float* c0;        // [128][512] fp32 or null (zeros)
  uint32_t* fown;         // [2][64] own per-WG flags (per batch-group)
  const uint32_t* fprod;  // [2][64] producer flags or null (prev-layer h ready)
  const uint32_t* fcons;  // [2][64] consumer flags or null (ring free / FC src)
  const float* fcw;       // [128][512] fp32 or null (dec0 only)
  const float* fcb;       // [128] fp32
  const uint16_t* fchr;   // dec1 h-ring (FC input)
  float* out;             // d_out [128][512][128] fp32
  int KX;                 // 128 or 512
  int shift;              // 1 for dec0 (input = x shifted right one step)
  int tsteps;             // 512, or 516 for dec0 (FC drain tail)
  uint32_t fb;            // flag base: 0 (phase A) or 512 (phase B)
};

__global__ void __launch_bounds__(256, 1) lstm_pipe(PJob j0, PJob j1) {
  const PJob J = ((int)blockIdx.x < 128) ? j0 : j1;
  const int lb = (int)blockIdx.x & 127;
  const int bg = lb >> 6, u = lb & 63, b0 = bg * 64;
  const int tid = (int)threadIdx.x;
  const int wv = tid >> 6, ln = tid & 63;

  __shared__ __align__(16) uint16_t Wl[40960];  // 64K rec weights + 16K fcW (80 KiB)
  __shared__ float gb[2][64][33];               // k-partial gates (+1 pad)
  __shared__ float cst[64][9];                  // fp32 cell state (+1 pad)
  __shared__ __align__(16) uint32_t hst[64][4]; // staged h slice (64 rows x 8 bf16)

  const int KX = J.KX;
  const int NTX = KX >> 5;          // x k-blocks per k-half (4 or 16)
  const int HS = (16 + NTX) * 512;  // packed elems per k-half

  // ---- gather [Whh ; Wih] chunk u from global fp32 -> LDS bf16 MFMA-B frags
  {
    const int nfrag = (2 * HS) >> 3;
    for (int f = tid; f < nfrag; f += 256) {
      int lane = f & 63;
      int kt2 = f >> 6;                       // kh*(16+NTX) + kt
      int kh = (kt2 >= 16 + NTX) ? 1 : 0;
      int kt = kt2 - kh * (16 + NTX);
      int col = lane & 31;
      int wrow = ((col >> 3) << 9) + (u << 3) + (col & 7);
      int m = (kt << 4) + ((lane >> 5) << 3);
      const float* src = (m < 256)
          ? J.whh + (size_t)wrow * 512 + (kh << 8) + m
          : J.wih + (size_t)wrow * KX + kh * (KX >> 1) + (m - 256);
      union { uint16_t h[8]; ulonglong2 v; } tmp;
#pragma unroll
      for (int j = 0; j < 8; ++j) tmp.h[j] = f2bf(src[j]);
      *(ulonglong2*)(Wl + (size_t)f * 8) = tmp.v;
    }
  }

  // FC assignment: dec0 WGs with u<8; wave wv owns out tile (ftr, ftc)
  const int isfc = (J.fcw != nullptr) && (u < 8);
  const int wgti = bg * 8 + u;             // 0..15
  const int ftc = wgti & 7;
  const int ftr = 2 * wv + (wgti >> 3);    // 0..7
  const int fcol = ftc * 16 + (ln & 15);
  const int farow = ftr * 16 + (ln & 15);
  float fbv = 0.0f;
  if (isfc) {
    fbv = J.fcb[fcol];
    for (int f = tid; f < 1024; f += 256) {
      int lane = f & 63, kt = f >> 6;
      int row = ftc * 16 + (lane & 15);
      int k = (kt << 5) + ((lane >> 4) << 3);
      const float* src = J.fcw + (size_t)row * 512 + k;
      union { uint16_t h[8]; ulonglong2 v; } tmp;
#pragma unroll
      for (int j = 0; j < 8; ++j) tmp.h[j] = f2bf(src[j]);
      *(ulonglong2*)(Wl + 32768 + (size_t)f * 8) = tmp.v;
    }
  }

  // ---- per-thread epilogue assignment: 2 hidden units ----
  const int rl = tid >> 2, ul2 = (tid & 3) * 2, bE = b0 + rl;
  const int hu = u * 8 + ul2;  // original hidden-unit index (pair base)
  const float Bi0 = J.bih[hu] + J.bhh[hu];
  const float Bi1 = J.bih[hu + 1] + J.bhh[hu + 1];
  const float Bf0 = J.bih[512 + hu] + J.bhh[512 + hu];
  const float Bf1 = J.bih[513 + hu] + J.bhh[513 + hu];
  const float Bg0 = J.bih[1024 + hu] + J.bhh[1024 + hu];
  const float Bg1 = J.bih[1025 + hu] + J.bhh[1025 + hu];
  const float Bo0 = J.bih[1536 + hu] + J.bhh[1536 + hu];
  const float Bo1 = J.bih[1537 + hu] + J.bhh[1537 + hu];
  {
    float c0v = 0.f, c1v = 0.f;
    if (J.c0) {
      c0v = J.c0[(size_t)bE * 512 + hu];
      c1v = J.c0[(size_t)bE * 512 + hu + 1];
    }
    cst[rl][ul2] = c0v;
    cst[rl][ul2 + 1] = c1v;
  }
  __syncthreads();

  const int mt = wv & 1, kh = wv >> 1;
  const int arow = b0 + mt * 32 + (ln & 31);
  const size_t hbase = (size_t)arow * 512 + (size_t)kh * 256 + ((ln >> 5) << 3);
  const uint16_t* wlh = Wl + (size_t)kh * HS + (size_t)ln * 8;
  const uint16_t* wlx = wlh + 16 * 512;
  const int tsteps = J.tsteps;
  const uint32_t FB = J.fb;

  for (int t = 0; t < tsteps; ++t) {
    f32x16 acc;
#pragma unroll
    for (int r = 0; r < 16; ++r) acc[r] = 0.0f;

    // ---- x-part from global fp32 (enc0/dec0): no cross-WG dep -> pre-wait
    if (t < 512 && J.xring == nullptr) {
      const int tx = t - J.shift;
      if (tx >= 0) {
        const float* xb = J.xf + (size_t)arow * (512 * (size_t)KX) +
                          (size_t)tx * KX + kh * (KX >> 1) + ((ln >> 5) << 3);
        for (int kt = 0; kt < NTX; ++kt) {
          bf16x8 af = cvt8(xb + kt * 16);
          acc = MFMA32(af, *(const bf16x8*)(wlx + kt * 512), acc);
        }
      }
    }

    // ---- cross-WG flag waits: wave 0, one flag per lane, parallel poll ----
    // w_own : peers' h(t-1) stored              (flags >= FB+t)
    // w_prod: prev layer's h(t) in its ring     (flags >= FB+t+1)
    // w_cons: next layer done step t-8 so plane (t+1)&7 is free (>= FB+t-7)
    // w_fc  : dec1 h(t-4) stored, both groups   (flags >= FB+t-3)
    if (wv == 0) {
      const uint32_t* po = J.fown + bg * 64;
      const uint32_t* pp = J.fprod ? J.fprod + bg * 64 : nullptr;
      const uint32_t* pc = J.fcons ? J.fcons + bg * 64 : nullptr;
      const uint32_t* pf = J.fcons;  // FC: both groups
      const int w_own  = (t >= 1) && (t < 512);
      const int w_prod = (pp != nullptr) && (t < 512);
      const int w_cons = (pc != nullptr) && (t >= 8) && (t < 512);
      const int w_fc   = isfc && (t >= 4);
      if (w_own | w_prod | w_cons | w_fc) {
        const uint32_t to  = FB + (uint32_t)t;
        const uint32_t tp  = to + 1u;
        const uint32_t tcn = to - 7u;
        const uint32_t tfc = to - 3u;
        while (1) {
          int ok = 1;
          if (w_own)  ok &= (aldf(po + ln) >= to);
          if (w_prod) ok &= (aldf(pp + ln) >= tp);
          if (w_cons) ok &= (aldf(pc + ln) >= tcn);
          if (w_fc) {
            ok &= (aldf(pf + ln) >= tfc);
            ok &= (aldf(pf + 64 + ln) >= tfc);
          }
          if (__all(ok)) break;
          __builtin_amdgcn_s_sleep(1);
        }
      }
    }
    __syncthreads();

    if (t < 512) {
      // h-part: K 256 per half, self 8-plane ring, 16B coherent loads
      const uint16_t* hb = J.hring + (size_t)(t & 7) * 65536 + hbase;
      bf16x8 ah[16];
#pragma unroll
      for (int kt = 0; kt < 16; ++kt) ldg16(ah[kt], hb + kt * 16);
      if (J.xring) {  // previous layer's h(t), plane (t+1)&7 of ITS ring
        const uint16_t* xb = J.xring + (size_t)((t + 1) & 7) * 65536 + hbase;
        bf16x8 ax[16];
#pragma unroll
        for (int kt = 0; kt < 16; ++kt) ldg16(ax[kt], xb + kt * 16);
        asm volatile("s_waitcnt vmcnt(0)" ::: "memory");
        __builtin_amdgcn_sched_barrier(0);
#pragma unroll
        for (int kt = 0; kt < 16; ++kt)
          acc = MFMA32(ah[kt], *(const bf16x8*)(wlh + kt * 512), acc);
#pragma unroll
        for (int kt = 0; kt < 16; ++kt)
          acc = MFMA32(ax[kt], *(const bf16x8*)(wlx + kt * 512), acc);
      } else {
        asm volatile("s_waitcnt vmcnt(0)" ::: "memory");
        __builtin_amdgcn_sched_barrier(0);
#pragma unroll
        for (int kt = 0; kt < 16; ++kt)
          acc = MFMA32(ah[kt], *(const bf16x8*)(wlh + kt * 512), acc);
      }
#pragma unroll
      for (int r = 0; r < 16; ++r) {
        int crow = (r & 3) + 8 * (r >> 2) + 4 * (ln >> 5);
        gb[kh][mt * 32 + crow][ln & 31] = acc[r];
      }
      __syncthreads();

      // ---- epilogue: 2 hidden units per thread; stage h slice in LDS ----
      float i0 = sigm(gb[0][rl][ul2]      + gb[1][rl][ul2]      + Bi0);
      float i1 = sigm(gb[0][rl][ul2 + 1]  + gb[1][rl][ul2 + 1]  + Bi1);
      float f0 = sigm(gb[0][rl][8 + ul2]  + gb[1][rl][8 + ul2]  + Bf0);
      float f1 = sigm(gb[0][rl][9 + ul2]  + gb[1][rl][9 + ul2]  + Bf1);
      float g0 = tanh_f(gb[0][rl][16 + ul2] + gb[1][rl][16 + ul2] + Bg0);
      float g1 = tanh_f(gb[0][rl][17 + ul2] + gb[1][rl][17 + ul2] + Bg1);
      float o0 = sigm(gb[0][rl][24 + ul2] + gb[1][rl][24 + ul2] + Bo0);
      float o1 = sigm(gb[0][rl][25 + ul2] + gb[1][rl][25 + ul2] + Bo1);
      float cc0 = f0 * cst[rl][ul2]     + i0 * g0;
      float cc1 = f1 * cst[rl][ul2 + 1] + i1 * g1;
      cst[rl][ul2] = cc0;
      cst[rl][ul2 + 1] = cc1;
      float h0 = o0 * tanh_f(cc0);
      float h1 = o1 * tanh_f(cc1);
      hst[rl][ul2 >> 1] = (uint32_t)f2bf(h0) | ((uint32_t)f2bf(h1) << 16);

      __syncthreads();  // hst ready for wave0

      // ---- wave0 alone: 64 x 16B coherent stores -> drain -> flag ----
      if (wv == 0) {
        u32x4 hv4;
#pragma unroll
        for (int q = 0; q < 4; ++q) hv4[q] = hst[ln][q];
        uint16_t* dst = J.hring + (size_t)((t + 1) & 7) * 65536 +
                        (size_t)(b0 + ln) * 512 + (size_t)(u << 3);
        stg16(dst, hv4);
        asm volatile("s_waitcnt vmcnt(0)" ::: "memory");
        if (ln == 0)
          __hip_atomic_store(J.fown + bg * 64 + u, FB + (uint32_t)(t + 1),
                             __ATOMIC_RELAXED, __HIP_MEMORY_SCOPE_AGENT);
      }
    }

    // ---- fused FC head: out[:, t-4] = dec1_h(t-4) @ fcW^T + fcb (fp32) ----
    if (isfc && t >= 4) {
      const int tf = t - 4;
      const uint16_t* ha = J.fchr + (size_t)((tf + 1) & 7) * 65536 +
                           (size_t)farow * 512 + ((ln >> 4) << 3);
      const uint16_t* wb = Wl + 32768 + (size_t)ln * 8;
      bf16x8 af[16];
#pragma unroll
      for (int kt = 0; kt < 16; ++kt) ldg16(af[kt], ha + kt * 32);
      asm volatile("s_waitcnt vmcnt(0)" ::: "memory");
      __builtin_amdgcn_sched_barrier(0);
      f32x4 fa;
      fa[0] = fa[1] = fa[2] = fa[3] = 0.0f;
#pragma unroll
      for (int kt = 0; kt < 16; ++kt)
        fa = MFMA16(af[kt], *(const bf16x8*)(wb + kt * 512), fa);
#pragma unroll
      for (int r = 0; r < 4; ++r) {
        int row = ftr * 16 + ((ln >> 4) << 2) + r;  // batch index
        J.out[((size_t)row * 512 + tf) * 128 + fcol] = fa[r] + fbv;
      }
    }
  }
}

// ---------------- host launch ----------------
extern "C" void kernel_launch(void* const* d_in, const int* in_sizes, int n_in,
                              void* d_out, int out_size, void* d_ws, size_t ws_size,
                              hipStream_t stream) {
  (void)in_sizes; (void)n_in; (void)out_size; (void)ws_size;
  uint8_t* ws = (uint8_t*)d_ws;
  const float* x     = (const float*)d_in[0];
  const float* c_dec = (const float*)d_in[1];
  const float* W[16];
  for (int i = 0; i < 16; ++i) W[i] = (const float*)d_in[2 + i];
  // layer order in d_in: enc0{wih,whh,bih,bhh} enc1{...} dec0{...} dec1{...}
  const float* fcW = (const float*)d_in[18];
  const float* fcb = (const float*)d_in[19];

  uint32_t* FLG = (uint32_t*)(ws + OFF_FLG);
  uint16_t* HB0 = (uint16_t*)(ws + OFF_HB0);
  uint16_t* HB1 = (uint16_t*)(ws + OFF_HB1);
  // flag arrays: [2][64] for layer0 (enc0/dec0), [2][64] for layer1
  uint32_t* FL0 = FLG + 0;    // L0: bg0 [0..63], bg1 [64..127]
  uint32_t* FL1 = FLG + 128;  // L1: bg0 [0..63], bg1 [64..127]

  // 1) zero flags + h-ring plane0 (h_{-1} = 0)
  hipLaunchKernelGGL(init_kernel, dim3(128), dim3(256), 0, stream,
                     FLG, (uint32_t*)HB0, (uint32_t*)HB1);

  // 2) phase A: enc0 (x -> HB0) || enc1 (HB0 -> HB1; seq discarded)
  {
    PJob a; a.whh = W[1]; a.wih = W[0]; a.bih = W[2]; a.bhh = W[3];
    a.xf = x; a.xring = nullptr; a.hring = HB0; a.c0 = nullptr;
    a.fown = FL0; a.fprod = nullptr; a.fcons = FL1;
    a.fcw = nullptr; a.fcb = nullptr; a.fchr = nullptr; a.out = nullptr;
    a.KX = 128; a.shift = 0; a.tsteps = 512; a.fb = 0;
    PJob b; b.whh = W[5]; b.wih = W[4]; b.bih = W[6]; b.bhh = W[7];
    b.xf = nullptr; b.xring = HB0; b.hring = HB1; b.c0 = nullptr;
    b.fown = FL1; b.fprod = FL0; b.fcons = nullptr;
    b.fcw = nullptr; b.fcb = nullptr; b.fchr = nullptr; b.out = nullptr;
    b.KX = 512; b.shift = 0; b.tsteps = 512; b.fb = 0;
    void* args[2] = { &a, &b };
    (void)hipLaunchCooperativeKernel((const void*)lstm_pipe, dim3(256), dim3(256), args, 0, stream);
  }

  // 3) phase B: dec0 (shift(x) -> HB0, h0 = enc0 hT in HB0 plane0, c0=c_dec[0],
  //    + fused FC from dec1's ring) || dec1 (HB0 -> HB1, h0 = enc1 hT, c0=c_dec[1])
  //    Flag arrays reused with fb=512 (phase A leaves every flag at exactly 512).
  {
    PJob a; a.whh = W[9]; a.wih = W[8]; a.bih = W[10]; a.bhh = W[11];
    a.xf = x; a.xring = nullptr; a.hring = HB0; a.c0 = c_dec;
    a.fown = FL0; a.fprod = nullptr; a.fcons = FL1;
    a.fcw = fcW; a.fcb = fcb; a.fchr = HB1; a.out = (float*)d_out;
    a.KX = 128; a.shift = 1; a.tsteps = 516; a.fb = 512;
    PJob b; b.whh = W[13]; b.wih = W[12]; b.bih = W[14]; b.bhh = W[15];
    b.xf = nullptr; b.xring = HB0; b.hring = HB1; b.c0 = c_dec + 65536;
    b.fown = FL1; b.fprod = FL0; b.fcons = nullptr;
    b.fcw = nullptr; b.fcb = nullptr; b.fchr = nullptr; b.out = nullptr;
    b.KX = 512; b.shift = 0; b.tsteps = 512; b.fb = 512;
    void* args[2] = { &a, &b };
    (void)hipLaunchCooperativeKernel((const void*)lstm_pipe, dim3(256), dim3(256), args, 0, stream);
  }
}

// Round 5
// 8427.817 us; speedup vs baseline: 1.7151x; 1.0320x over previous
//
#include <hip/hip_runtime.h>
#include <stdint.h>

// ============================================================================
// RecurrentAutoEncoder (2-layer LSTM enc + 2-layer LSTM dec + FC).
// ALL inputs/outputs are FP32 (per reference). Internally: bf16 MFMA
// fragments, fp32 accum.
//   Phase A (coop, 256 WGs): enc0 --hring--> enc1  (enc1 seq discarded)
//   Phase B (coop, 256 WGs): dec0 --hring--> dec1 --(delay 4)--> fused FC
// h buffers: P-plane bf16 rings; enc->dec h_T handoff free (512 % P == 0).
//
// v2: per-WG flags + relaxed agent (sc0sc1) data path: 24 -> 13.6 us/step.
// v3 (REFUTED): L2-caching + PER-STEP buffer_inv storm: -10% + 58ms outlier.
// v4: LDS-gathered 16B h-stores, ringout removed, 16B loads: 13.6 -> 8.9
//     us/step. Confirmed: we are MALL TRANSACTION-RATE bound.
// v5 (this round): kill the 64x broadcast READ amplification.
//   * consumer ring loads: sc0-only (L1 bypass, L2 ALLOCATE) -> 32 WGs/XCD
//     share one L2 copy instead of 64 separate MALL round-trips.
//   * staleness: h-rings enlarged 8 -> P=64 planes (reuse distance 64 steps);
//     each WG issues ONE agent-acquire (buffer_inv) every IP=P-8 steps,
//     staggered by u, + at t=0 (cross-phase/iteration staleness). A WG
//     re-reads an address only after P of its own steps; its own period-IP
//     inv always lands in that window -> fresh MALL fetch. ~2.3 invs/step
//     device-wide (v3 had 1024/step).
//   * everything that must survive an inv is write-through sc0sc1: h-rings
//     (already), FC out (new), init stores (new).
//   * ws_size-adaptive: P=64 (16.8MB) / P=32 (8.4MB) cached; else P=8
//     UNCACHED fallback == v4 exactly.
// ============================================================================

using bf16x8 = __attribute__((ext_vector_type(8))) short;   // 8 bf16 = 4 VGPR
using u32x4  = __attribute__((ext_vector_type(4))) uint32_t; // 4 VGPR payload
using f32x16 = __attribute__((ext_vector_type(16))) float;  // 32x32 mfma acc
using f32x4  = __attribute__((ext_vector_type(4))) float;   // 16x16 mfma acc

#define MFMA32(a, b, c) __builtin_amdgcn_mfma_f32_32x32x16_bf16((a), (b), (c), 0, 0, 0)
#define MFMA16(a, b, c) __builtin_amdgcn_mfma_f32_16x16x32_bf16((a), (b), (c), 0, 0, 0)

static __device__ __forceinline__ uint16_t f2bf(float f) {
  union { float f; uint32_t u; } v; v.f = f;
  uint32_t u = v.u;
  return (uint16_t)((u + 0x7fffu + ((u >> 16) & 1u)) >> 16);  // RNE
}
static __device__ __forceinline__ float sigm(float x) { return 1.0f / (1.0f + __expf(-x)); }
static __device__ __forceinline__ float tanh_f(float x) { return 2.0f / (1.0f + __expf(-2.0f * x)) - 1.0f; }

static __device__ __forceinline__ bf16x8 cvt8(const float* p) {
  bf16x8 r;
#pragma unroll
  for (int i = 0; i < 8; ++i) { uint16_t b = f2bf(p[i]); r[i] = (short)b; }
  return r;
}

// ---- sync/data helpers ----
// flag loads: full bypass -- must always see fresh MALL state.
static __device__ __forceinline__ uint32_t aldf(const uint32_t* p) {
  return __hip_atomic_load(p, __ATOMIC_RELAXED, __HIP_MEMORY_SCOPE_AGENT);
}
// 16B ring load, CACHED variant: bypass L1, ALLOCATE in L2 (sc0 only).
static __device__ __forceinline__ void ldg16_c(bf16x8& d, const uint16_t* p) {
  asm volatile("global_load_dwordx4 %0, %1, off sc0" : "=v"(d) : "v"(p) : "memory");
}
// 16B ring load, UNCACHED variant (v4 path): bypass L1+L2.
static __device__ __forceinline__ void ldg16_u(bf16x8& d, const uint16_t* p) {
  asm volatile("global_load_dwordx4 %0, %1, off sc0 sc1" : "=v"(d) : "v"(p) : "memory");
}
template <int C>
static __device__ __forceinline__ void ldg16(bf16x8& d, const uint16_t* p) {
  if (C) ldg16_c(d, p); else ldg16_u(d, p);
}
// 16B coherent write-through store
static __device__ __forceinline__ void stg16(uint16_t* p, u32x4 v) {
  asm volatile("global_store_dwordx4 %0, %1, off sc0 sc1" :: "v"(p), "v"(v) : "memory");
}
// 4B coherent write-through store (FC out: must survive buffer_inv)
static __device__ __forceinline__ void stgf(float* p, float v) {
  asm volatile("global_store_dword %0, %1, off sc0 sc1" :: "v"(p), "v"(v) : "memory");
}
// agent acquire: emits s_waitcnt + buffer_inv (L2 invalidate). Per-wave:
// this wave's subsequent loads are program-ordered after the inv.
static __device__ __forceinline__ void l2_acquire(const uint32_t* p) {
  (void)__hip_atomic_load(p, __ATOMIC_ACQUIRE, __HIP_MEMORY_SCOPE_AGENT);
}

// ---------------- workspace layout ----------------
// [0,1024)          : [4][64] u32 per-WG step flags
// [1024, +P*128K)   : HB0  [P][128][512] bf16 h-ring (enc0/dec0)
// [.., +P*128K)     : HB1  [P][128][512] bf16 h-ring (enc1/dec1)
// P chosen host-side from ws_size: 64 / 32 (cached) or 8 (uncached fallback).

// ---------------- init: zero flags + h-ring plane0 (h_{-1}=0) ------------
// Stores are write-through agent-scope: cached consumers must see them at
// MALL (plain stores would stay dirty in this kernel's XCD L2s).
__global__ void init_kernel(uint32_t* flg, uint32_t* h0a, uint32_t* h0b) {
  int i = (int)blockIdx.x * 256 + (int)threadIdx.x;
  if (i < 256) __hip_atomic_store(flg + i, 0u, __ATOMIC_RELAXED, __HIP_MEMORY_SCOPE_AGENT);
  for (int j = i; j < 32768; j += (int)gridDim.x * 256) {
    __hip_atomic_store(h0a + j, 0u, __ATOMIC_RELAXED, __HIP_MEMORY_SCOPE_AGENT);
    __hip_atomic_store(h0b + j, 0u, __ATOMIC_RELAXED, __HIP_MEMORY_SCOPE_AGENT);
  }
}

// ---------------- pipelined persistent LSTM layer kernel ----------------
struct PJob {
  const float* whh;       // [2048][512] fp32
  const float* wih;       // [2048][KX] fp32
  const float* bih;       // [2048] fp32
  const float* bhh;       // [2048] fp32
  const float* xf;        // fp32 x [128][512][KX] (enc0/dec0) or null
  const uint16_t* xring;  // producer's P-plane h-ring (enc1/dec1) or null
  uint16_t* hring;        // [P][128][512] bf16; plane0 = h_{-1}
  const float* c0;        // [128][512] fp32 or null (zeros)
  uint32_t* fown;         // [2][64] own per-WG flags (per batch-group)
  const uint32_t* fprod;  // [2][64] producer flags or null (prev-layer h ready)
  const uint32_t* fcons;  // [2][64] consumer flags or null (ring free / FC src)
  const float* fcw;       // [128][512] fp32 or null (dec0 only)
  const float* fcb;       // [128] fp32
  const uint16_t* fchr;   // dec1 h-ring (FC input)
  float* out;             // d_out [128][512][128] fp32
  int KX;                 // 128 or 512
  int shift;              // 1 for dec0 (input = x shifted right one step)
  int tsteps;             // 512, or 516 for dec0 (FC drain tail)
  uint32_t fb;            // flag base: 0 (phase A) or 512 (phase B)
  int pm;                 // plane mask = P-1 (P a power of 2, P | 512)
  int ivp;                // inv period (P-8); only used when CACHED
};

template <int CACHED>
__global__ void __launch_bounds__(256, 1) lstm_pipe(PJob j0, PJob j1) {
  const PJob J = ((int)blockIdx.x < 128) ? j0 : j1;
  const int lb = (int)blockIdx.x & 127;
  const int bg = lb >> 6, u = lb & 63, b0 = bg * 64;
  const int tid = (int)threadIdx.x;
  const int wv = tid >> 6, ln = tid & 63;

  __shared__ __align__(16) uint16_t Wl[40960];  // 64K rec weights + 16K fcW (80 KiB)
  __shared__ float gb[2][64][33];               // k-partial gates (+1 pad)
  __shared__ float cst[64][9];                  // fp32 cell state (+1 pad)
  __shared__ __align__(16) uint32_t hst[64][4]; // staged h slice (64 rows x 8 bf16)

  const int KX = J.KX;
  const int NTX = KX >> 5;          // x k-blocks per k-half (4 or 16)
  const int HS = (16 + NTX) * 512;  // packed elems per k-half

  // ---- gather [Whh ; Wih] chunk u from global fp32 -> LDS bf16 MFMA-B frags
  {
    const int nfrag = (2 * HS) >> 3;
    for (int f = tid; f < nfrag; f += 256) {
      int lane = f & 63;
      int kt2 = f >> 6;                       // kh*(16+NTX) + kt
      int kh = (kt2 >= 16 + NTX) ? 1 : 0;
      int kt = kt2 - kh * (16 + NTX);
      int col = lane & 31;
      int wrow = ((col >> 3) << 9) + (u << 3) + (col & 7);
      int m = (kt << 4) + ((lane >> 5) << 3);
      const float* src = (m < 256)
          ? J.whh + (size_t)wrow * 512 + (kh << 8) + m
          : J.wih + (size_t)wrow * KX + kh * (KX >> 1) + (m - 256);
      union { uint16_t h[8]; ulonglong2 v; } tmp;
#pragma unroll
      for (int j = 0; j < 8; ++j) tmp.h[j] = f2bf(src[j]);
      *(ulonglong2*)(Wl + (size_t)f * 8) = tmp.v;
    }
  }

  // FC assignment: dec0 WGs with u<8; wave wv owns out tile (ftr, ftc)
  const int isfc = (J.fcw != nullptr) && (u < 8);
  const int wgti = bg * 8 + u;             // 0..15
  const int ftc = wgti & 7;
  const int ftr = 2 * wv + (wgti >> 3);    // 0..7
  const int fcol = ftc * 16 + (ln & 15);
  const int farow = ftr * 16 + (ln & 15);
  float fbv = 0.0f;
  if (isfc) {
    fbv = J.fcb[fcol];
    for (int f = tid; f < 1024; f += 256) {
      int lane = f & 63, kt = f >> 6;
      int row = ftc * 16 + (lane & 15);
      int k = (kt << 5) + ((lane >> 4) << 3);
      const float* src = J.fcw + (size_t)row * 512 + k;
      union { uint16_t h[8]; ulonglong2 v; } tmp;
#pragma unroll
      for (int j = 0; j < 8; ++j) tmp.h[j] = f2bf(src[j]);
      *(ulonglong2*)(Wl + 32768 + (size_t)f * 8) = tmp.v;
    }
  }

  // ---- per-thread epilogue assignment: 2 hidden units ----
  const int rl = tid >> 2, ul2 = (tid & 3) * 2, bE = b0 + rl;
  const int hu = u * 8 + ul2;  // original hidden-unit index (pair base)
  const float Bi0 = J.bih[hu] + J.bhh[hu];
  const float Bi1 = J.bih[hu + 1] + J.bhh[hu + 1];
  const float Bf0 = J.bih[512 + hu] + J.bhh[512 + hu];
  const float Bf1 = J.bih[513 + hu] + J.bhh[513 + hu];
  const float Bg0 = J.bih[1024 + hu] + J.bhh[1024 + hu];
  const float Bg1 = J.bih[1025 + hu] + J.bhh[1025 + hu];
  const float Bo0 = J.bih[1536 + hu] + J.bhh[1536 + hu];
  const float Bo1 = J.bih[1537 + hu] + J.bhh[1537 + hu];
  {
    float c0v = 0.f, c1v = 0.f;
    if (J.c0) {
      c0v = J.c0[(size_t)bE * 512 + hu];
      c1v = J.c0[(size_t)bE * 512 + hu + 1];
    }
    cst[rl][ul2] = c0v;
    cst[rl][ul2 + 1] = c1v;
  }
  __syncthreads();

  const int mt = wv & 1, kh = wv >> 1;
  const int arow = b0 + mt * 32 + (ln & 31);
  const size_t hbase = (size_t)arow * 512 + (size_t)kh * 256 + ((ln >> 5) << 3);
  const uint16_t* wlh = Wl + (size_t)kh * HS + (size_t)ln * 8;
  const uint16_t* wlx = wlh + 16 * 512;
  const int tsteps = J.tsteps;
  const uint32_t FB = J.fb;
  const int pm = J.pm;           // plane mask
  const int PP = pm + 1;         // plane count

  for (int t = 0; t < tsteps; ++t) {
    f32x16 acc;
#pragma unroll
    for (int r = 0; r < 16; ++r) acc[r] = 0.0f;

    // ---- x-part from global fp32 (enc0/dec0): no cross-WG dep -> pre-wait
    if (t < 512 && J.xring == nullptr) {
      const int tx = t - J.shift;
      if (tx >= 0) {
        const float* xb = J.xf + (size_t)arow * (512 * (size_t)KX) +
                          (size_t)tx * KX + kh * (KX >> 1) + ((ln >> 5) << 3);
        for (int kt = 0; kt < NTX; ++kt) {
          bf16x8 af = cvt8(xb + kt * 16);
          acc = MFMA32(af, *(const bf16x8*)(wlx + kt * 512), acc);
        }
      }
    }

    // ---- cross-WG flag waits: wave 0, one flag per lane, parallel poll ----
    // w_own : peers' h(t-1) stored              (flags >= FB+t)
    // w_prod: prev layer's h(t) in its ring     (flags >= FB+t+1)
    // w_cons: ring reader done step t-P so plane (t+1)&pm is free (>= FB+t-(P-1))
    // w_fc  : dec1 h(t-4) stored, both groups   (flags >= FB+t-3)
    if (wv == 0) {
      const uint32_t* po = J.fown + bg * 64;
      const uint32_t* pp = J.fprod ? J.fprod + bg * 64 : nullptr;
      const uint32_t* pc = J.fcons ? J.fcons + bg * 64 : nullptr;
      const uint32_t* pf = J.fcons;  // FC: both groups
      const int w_own  = (t >= 1) && (t < 512);
      const int w_prod = (pp != nullptr) && (t < 512);
      const int w_cons = (pc != nullptr) && (t >= PP) && (t < 512);
      const int w_fc   = isfc && (t >= 4);
      if (w_own | w_prod | w_cons | w_fc) {
        const uint32_t to  = FB + (uint32_t)t;
        const uint32_t tp  = to + 1u;
        const uint32_t tcn = to - (uint32_t)(PP - 1);
        const uint32_t tfc = to - 3u;
        while (1) {
          int ok = 1;
          if (w_own)  ok &= (aldf(po + ln) >= to);
          if (w_prod) ok &= (aldf(pp + ln) >= tp);
          if (w_cons) ok &= (aldf(pc + ln) >= tcn);
          if (w_fc) {
            ok &= (aldf(pf + ln) >= tfc);
            ok &= (aldf(pf + 64 + ln) >= tfc);
          }
          if (__all(ok)) break;
          __builtin_amdgcn_s_sleep(1);
        }
      }
    }
    __syncthreads();

    // ---- rare L2 invalidate (CACHED only): every wave, so each wave's own
    // subsequent loads are program-ordered after its own inv. Period ivp =
    // P-8 < P guarantees: between a WG's two reads of the same ring address
    // (exactly P own-steps apart) there is always one own inv. t==0 covers
    // cross-phase and cross-dispatch-iteration staleness. Staggered by u.
    if (CACHED) {
      if ((t == 0) || (((uint32_t)(t + u * 5) % (uint32_t)J.ivp) == 0)) {
        l2_acquire(J.fown + bg * 64 + u);
      }
    }

    if (t < 512) {
      // h-part: K 256 per half, self P-plane ring, 16B loads
      const uint16_t* hb = J.hring + (size_t)(t & pm) * 65536 + hbase;
      bf16x8 ah[16];
#pragma unroll
      for (int kt = 0; kt < 16; ++kt) ldg16<CACHED>(ah[kt], hb + kt * 16);
      if (J.xring) {  // previous layer's h(t), plane (t+1)&pm of ITS ring
        const uint16_t* xb = J.xring + (size_t)((t + 1) & pm) * 65536 + hbase;
        bf16x8 ax[16];
#pragma unroll
        for (int kt = 0; kt < 16; ++kt) ldg16<CACHED>(ax[kt], xb + kt * 16);
        asm volatile("s_waitcnt vmcnt(0)" ::: "memory");
        __builtin_amdgcn_sched_barrier(0);
#pragma unroll
        for (int kt = 0; kt < 16; ++kt)
          acc = MFMA32(ah[kt], *(const bf16x8*)(wlh + kt * 512), acc);
#pragma unroll
        for (int kt = 0; kt < 16; ++kt)
          acc = MFMA32(ax[kt], *(const bf16x8*)(wlx + kt * 512), acc);
      } else {
        asm volatile("s_waitcnt vmcnt(0)" ::: "memory");
        __builtin_amdgcn_sched_barrier(0);
#pragma unroll
        for (int kt = 0; kt < 16; ++kt)
          acc = MFMA32(ah[kt], *(const bf16x8*)(wlh + kt * 512), acc);
      }
#pragma unroll
      for (int r = 0; r < 16; ++r) {
        int crow = (r & 3) + 8 * (r >> 2) + 4 * (ln >> 5);
        gb[kh][mt * 32 + crow][ln & 31] = acc[r];
      }
      __syncthreads();

      // ---- epilogue: 2 hidden units per thread; stage h slice in LDS ----
      float i0 = sigm(gb[0][rl][ul2]      + gb[1][rl][ul2]      + Bi0);
      float i1 = sigm(gb[0][rl][ul2 + 1]  + gb[1][rl][ul2 + 1]  + Bi1);
      float f0 = sigm(gb[0][rl][8 + ul2]  + gb[1][rl][8 + ul2]  + Bf0);
      float f1 = sigm(gb[0][rl][9 + ul2]  + gb[1][rl][9 + ul2]  + Bf1);
      float g0 = tanh_f(gb[0][rl][16 + ul2] + gb[1][rl][16 + ul2] + Bg0);
      float g1 = tanh_f(gb[0][rl][17 + ul2] + gb[1][rl][17 + ul2] + Bg1);
      float o0 = sigm(gb[0][rl][24 + ul2] + gb[1][rl][24 + ul2] + Bo0);
      float o1 = sigm(gb[0][rl][25 + ul2] + gb[1][rl][25 + ul2] + Bo1);
      float cc0 = f0 * cst[rl][ul2]     + i0 * g0;
      float cc1 = f1 * cst[rl][ul2 + 1] + i1 * g1;
      cst[rl][ul2] = cc0;
      cst[rl][ul2 + 1] = cc1;
      float h0 = o0 * tanh_f(cc0);
      float h1 = o1 * tanh_f(cc1);
      hst[rl][ul2 >> 1] = (uint32_t)f2bf(h0) | ((uint32_t)f2bf(h1) << 16);

      __syncthreads();  // hst ready for wave0

      // ---- wave0 alone: 64 x 16B write-through stores -> drain -> flag ----
      if (wv == 0) {
        u32x4 hv4;
#pragma unroll
        for (int q = 0; q < 4; ++q) hv4[q] = hst[ln][q];
        uint16_t* dst = J.hring + (size_t)((t + 1) & pm) * 65536 +
                        (size_t)(b0 + ln) * 512 + (size_t)(u << 3);
        stg16(dst, hv4);
        asm volatile("s_waitcnt vmcnt(0)" ::: "memory");
        if (ln == 0)
          __hip_atomic_store(J.fown + bg * 64 + u, FB + (uint32_t)(t + 1),
                             __ATOMIC_RELAXED, __HIP_MEMORY_SCOPE_AGENT);
      }
    }

    // ---- fused FC head: out[:, t-4] = dec1_h(t-4) @ fcW^T + fcb (fp32) ----
    if (isfc && t >= 4) {
      const int tf = t - 4;
      const uint16_t* ha = J.fchr + (size_t)((tf + 1) & pm) * 65536 +
                           (size_t)farow * 512 + ((ln >> 4) << 3);
      const uint16_t* wb = Wl + 32768 + (size_t)ln * 8;
      bf16x8 af[16];
#pragma unroll
      for (int kt = 0; kt < 16; ++kt) ldg16<CACHED>(af[kt], ha + kt * 32);
      asm volatile("s_waitcnt vmcnt(0)" ::: "memory");
      __builtin_amdgcn_sched_barrier(0);
      f32x4 fa;
      fa[0] = fa[1] = fa[2] = fa[3] = 0.0f;
#pragma unroll
      for (int kt = 0; kt < 16; ++kt)
        fa = MFMA16(af[kt], *(const bf16x8*)(wb + kt * 512), fa);
#pragma unroll
      for (int r = 0; r < 4; ++r) {
        int row = ftr * 16 + ((ln >> 4) << 2) + r;  // batch index
        stgf(&J.out[((size_t)row * 512 + tf) * 128 + fcol], fa[r] + fbv);
      }
    }
  }
}

// ---------------- host launch ----------------
extern "C" void kernel_launch(void* const* d_in, const int* in_sizes, int n_in,
                              void* d_out, int out_size, void* d_ws, size_t ws_size,
                              hipStream_t stream) {
  (void)in_sizes; (void)n_in; (void)out_size;
  uint8_t* ws = (uint8_t*)d_ws;
  const float* x     = (const float*)d_in[0];
  const float* c_dec = (const float*)d_in[1];
  const float* W[16];
  for (int i = 0; i < 16; ++i) W[i] = (const float*)d_in[2 + i];
  // layer order in d_in: enc0{wih,whh,bih,bhh} enc1{...} dec0{...} dec1{...}
  const float* fcW = (const float*)d_in[18];
  const float* fcb = (const float*)d_in[19];

  // ---- choose ring depth P from ws_size (plane = 128KB) ----
  int P, cached;
  if (ws_size >= 1024 + 2ull * 64 * 131072) { P = 64; cached = 1; }
  else if (ws_size >= 1024 + 2ull * 32 * 131072) { P = 32; cached = 1; }
  else { P = 8; cached = 0; }  // v4-identical fallback
  const int IP = P - 8;        // inv period (unused when !cached)

  uint32_t* FLG = (uint32_t*)(ws + 0);
  uint16_t* HB0 = (uint16_t*)(ws + 1024);
  uint16_t* HB1 = (uint16_t*)(ws + 1024 + (size_t)P * 131072);
  // flag arrays: [2][64] for layer0 (enc0/dec0), [2][64] for layer1
  uint32_t* FL0 = FLG + 0;    // L0: bg0 [0..63], bg1 [64..127]
  uint32_t* FL1 = FLG + 128;  // L1: bg0 [0..63], bg1 [64..127]

  const void* kern = cached ? (const void*)lstm_pipe<1> : (const void*)lstm_pipe<0>;

  // 1) zero flags + h-ring plane0 (h_{-1} = 0), write-through
  hipLaunchKernelGGL(init_kernel, dim3(128), dim3(256), 0, stream,
                     FLG, (uint32_t*)HB0, (uint32_t*)HB1);

  // 2) phase A: enc0 (x -> HB0) || enc1 (HB0 -> HB1; seq discarded)
  {
    PJob a; a.whh = W[1]; a.wih = W[0]; a.bih = W[2]; a.bhh = W[3];
    a.xf = x; a.xring = nullptr; a.hring = HB0; a.c0 = nullptr;
    a.fown = FL0; a.fprod = nullptr; a.fcons = FL1;
    a.fcw = nullptr; a.fcb = nullptr; a.fchr = nullptr; a.out = nullptr;
    a.KX = 128; a.shift = 0; a.tsteps = 512; a.fb = 0; a.pm = P - 1; a.ivp = IP;
    PJob b; b.whh = W[5]; b.wih = W[4]; b.bih = W[6]; b.bhh = W[7];
    b.xf = nullptr; b.xring = HB0; b.hring = HB1; b.c0 = nullptr;
    b.fown = FL1; b.fprod = FL0; b.fcons = nullptr;
    b.fcw = nullptr; b.fcb = nullptr; b.fchr = nullptr; b.out = nullptr;
    b.KX = 512; b.shift = 0; b.tsteps = 512; b.fb = 0; b.pm = P - 1; b.ivp = IP;
    void* args[2] = { &a, &b };
    (void)hipLaunchCooperativeKernel(kern, dim3(256), dim3(256), args, 0, stream);
  }

  // 3) phase B: dec0 (shift(x) -> HB0, h0 = enc0 hT in HB0 plane0, c0=c_dec[0],
  //    + fused FC from dec1's ring) || dec1 (HB0 -> HB1, h0 = enc1 hT, c0=c_dec[1])
  //    Flag arrays reused with fb=512 (phase A leaves every flag at exactly 512;
  //    512 % P == 0 so the h_T handoff lands in plane 0 of each ring).
  {
    PJob a; a.whh = W[9]; a.wih = W[8]; a.bih = W[10]; a.bhh = W[11];
    a.xf = x; a.xring = nullptr; a.hring = HB0; a.c0 = c_dec;
    a.fown = FL0; a.fprod = nullptr; a.fcons = FL1;
    a.fcw = fcW; a.fcb = fcb; a.fchr = HB1; a.out = (float*)d_out;
    a.KX = 128; a.shift = 1; a.tsteps = 516; a.fb = 512; a.pm = P - 1; a.ivp = IP;
    PJob b; b.whh = W[13]; b.wih = W[12]; b.bih = W[14]; b.bhh = W[15];
    b.xf = nullptr; b.xring = HB0; b.hring = HB1; b.c0 = c_dec + 65536;
    b.fown = FL1; b.fprod = FL0; b.fcons = nullptr;
    b.fcw = nullptr; b.fcb = nullptr; b.fchr = nullptr; b.out = nullptr;
    b.KX = 512; b.shift = 0; b.tsteps = 512; b.fb = 512; b.pm = P - 1; b.ivp = IP;
    void* args[2] = { &a, &b };
    (void)hipLaunchCooperativeKernel(kern, dim3(256), dim3(256), args, 0, stream);
  }
}

// Round 8
// 8125.467 us; speedup vs baseline: 1.7790x; 1.0372x over previous
//
#include <hip/hip_runtime.h>
#include <stdint.h>

// ============================================================================
// RecurrentAutoEncoder (2-layer LSTM enc + 2-layer LSTM dec + FC).
// ALL inputs/outputs are FP32 (per reference). Internally: bf16 MFMA
// fragments, fp32 accum.
//   Phase A (coop, 256 WGs): enc0 --hring--> enc1  (enc1 seq discarded)
//   Phase B (coop, 256 WGs): dec0 --hring--> dec1 --(delay 4)--> fused FC
// h buffers: 8-plane bf16 rings; enc->dec h_T handoff free (512 % 8 == 0).
//
// v2: per-WG flags + relaxed agent (sc0sc1) data path: 24 -> 13.6 us/step.
// v3 (REFUTED): L2-caching + per-step buffer_inv storm.
// v4 (PASSED, 8697us): LDS-gathered 16B h-stores, no ringout, 16B loads.
// v5 (REFUTED): L2-cached rings + periodic invs (granularity too coarse).
// v6/v7 (FAILED, IDENTICAL absmax): shared defect diagnosed as VGPR-pressure
//     spills of inline-asm load destinations (spill-store reads a VGPR whose
//     defining global_load is still in flight; compiler can't know an asm
//     "=v" output is vmcnt-pending) -> deterministic garbage. v4 (132 VGPR)
//     never spills.
// v8 (this round): v4 EXACTLY + two pressure-bounded deltas only:
//   * counted vmcnt(16) pipeline in the xring branch (same ah/ax arrays,
//     zero new regs): MFMA on ah while ax still in flight. vmcnt retires
//     in issue order -> vmcnt(16) guarantees ah complete.
//   * dual accumulators (+16 VGPR, ~148 total) halve the exposed 16-deep
//     dependent-MFMA chain.
//   Wave0-only poll + post-poll __syncthreads kept EXACTLY as v4.
// d_ws footprint: 2.1 MiB.
// ============================================================================

using bf16x8 = __attribute__((ext_vector_type(8))) short;    // 8 bf16 = 4 VGPR
using u32x4  = __attribute__((ext_vector_type(4))) uint32_t; // 4 VGPR payload
using f32x16 = __attribute__((ext_vector_type(16))) float;   // 32x32 mfma acc
using f32x4  = __attribute__((ext_vector_type(4))) float;    // 16x16 mfma acc

#define MFMA32(a, b, c) __builtin_amdgcn_mfma_f32_32x32x16_bf16((a), (b), (c), 0, 0, 0)
#define MFMA16(a, b, c) __builtin_amdgcn_mfma_f32_16x16x32_bf16((a), (b), (c), 0, 0, 0)
#define VMCNT0()  asm volatile("s_waitcnt vmcnt(0)" ::: "memory")
#define VMCNT16() asm volatile("s_waitcnt vmcnt(16)" ::: "memory")
#define SCHEDB()  __builtin_amdgcn_sched_barrier(0)

static __device__ __forceinline__ uint16_t f2bf(float f) {
  union { float f; uint32_t u; } v; v.f = f;
  uint32_t u = v.u;
  return (uint16_t)((u + 0x7fffu + ((u >> 16) & 1u)) >> 16);  // RNE
}
static __device__ __forceinline__ float sigm(float x) { return 1.0f / (1.0f + __expf(-x)); }
static __device__ __forceinline__ float tanh_f(float x) { return 2.0f / (1.0f + __expf(-2.0f * x)) - 1.0f; }

static __device__ __forceinline__ bf16x8 cvt8(const float* p) {
  bf16x8 r;
#pragma unroll
  for (int i = 0; i < 8; ++i) { uint16_t b = f2bf(p[i]); r[i] = (short)b; }
  return r;
}

// ---- sync/data helpers (device-coherent, no cache-maintenance ops) ----
static __device__ __forceinline__ uint32_t aldf(const uint32_t* p) {
  return __hip_atomic_load(p, __ATOMIC_RELAXED, __HIP_MEMORY_SCOPE_AGENT);
}
// 16B coherent load, raw asm: caller must waitcnt + sched_barrier before use
static __device__ __forceinline__ void ldg16(bf16x8& d, const uint16_t* p) {
  asm volatile("global_load_dwordx4 %0, %1, off sc0 sc1" : "=v"(d) : "v"(p) : "memory");
}
// 16B coherent write-through store (payload must be ext_vector_type for "v")
static __device__ __forceinline__ void stg16(uint16_t* p, u32x4 v) {
  asm volatile("global_store_dwordx4 %0, %1, off sc0 sc1" :: "v"(p), "v"(v) : "memory");
}

// ---------------- workspace layout (bytes); total 2,098,176 B ----------------
static const size_t OFF_FLG = 0;                  // [4][64] u32 per-WG step flags
static const size_t OFF_HB0 = 1024;               // [8][128][512] bf16 h-ring (enc0/dec0)
static const size_t OFF_HB1 = 1024 + 1048576;     // [8][128][512] bf16 h-ring (enc1/dec1)

// ---------------- init: zero flags + h-ring plane0 (h_{-1}=0) ------------
__global__ void init_kernel(uint32_t* flg, uint32_t* h0a, uint32_t* h0b) {
  int i = (int)blockIdx.x * 256 + (int)threadIdx.x;
  if (i < 256) __hip_atomic_store(flg + i, 0u, __ATOMIC_RELAXED, __HIP_MEMORY_SCOPE_AGENT);
  for (int j = i; j < 32768; j += (int)gridDim.x * 256) {
    __hip_atomic_store(h0a + j, 0u, __ATOMIC_RELAXED, __HIP_MEMORY_SCOPE_AGENT);
    __hip_atomic_store(h0b + j, 0u, __ATOMIC_RELAXED, __HIP_MEMORY_SCOPE_AGENT);
  }
}

// ---------------- pipelined persistent LSTM layer kernel ----------------
struct PJob {
  const float* whh;       // [2048][512] fp32
  const float* wih;       // [2048][KX] fp32
  const float* bih;       // [2048] fp32
  const float* bhh;       // [2048] fp32
  const float* xf;        // fp32 x [128][512][KX] (enc0/dec0) or null
  const uint16_t* xring;  // producer's 8-plane h-ring (enc1/dec1) or null
  uint16_t* hring;        // [8][128][512] bf16; plane0 = h_{-1}
  const float* c0;        // [128][512] fp32 or null (zeros)
  uint32_t* fown;         // [2][64] own per-WG flags (per batch-group)
  const uint32_t* fprod;  // [2][64] producer flags or null (prev-layer h ready)
  const uint32_t* fcons;  // [2][64] consumer flags or null (ring free / FC src)
  const float* fcw;       // [128][512] fp32 or null (dec0 only)
  const float* fcb;       // [128] fp32
  const uint16_t* fchr;   // dec1 h-ring (FC input)
  float* out;             // d_out [128][512][128] fp32
  int KX;                 // 128 or 512
  int shift;              // 1 for dec0 (input = x shifted right one step)
  int tsteps;             // 512, or 516 for dec0 (FC drain tail)
  uint32_t fb;            // flag base: 0 (phase A) or 512 (phase B)
};

__global__ void __launch_bounds__(256, 1) lstm_pipe(PJob j0, PJob j1) {
  const PJob J = ((int)blockIdx.x < 128) ? j0 : j1;
  const int lb = (int)blockIdx.x & 127;
  const int bg = lb >> 6, u = lb & 63, b0 = bg * 64;
  const int tid = (int)threadIdx.x;
  const int wv = tid >> 6, ln = tid & 63;

  __shared__ __align__(16) uint16_t Wl[40960];  // 64K rec weights + 16K fcW (80 KiB)
  __shared__ float gb[2][64][33];               // k-partial gates (+1 pad)
  __shared__ float cst[64][9];                  // fp32 cell state (+1 pad)
  __shared__ __align__(16) uint32_t hst[64][4]; // staged h slice (64 rows x 8 bf16)

  const int KX = J.KX;
  const int NTX = KX >> 5;          // x k-blocks per k-half (4 or 16)
  const int HS = (16 + NTX) * 512;  // packed elems per k-half

  // ---- gather [Whh ; Wih] chunk u from global fp32 -> LDS bf16 MFMA-B frags
  {
    const int nfrag = (2 * HS) >> 3;
    for (int f = tid; f < nfrag; f += 256) {
      int lane = f & 63;
      int kt2 = f >> 6;                       // kh*(16+NTX) + kt
      int kh = (kt2 >= 16 + NTX) ? 1 : 0;
      int kt = kt2 - kh * (16 + NTX);
      int col = lane & 31;
      int wrow = ((col >> 3) << 9) + (u << 3) + (col & 7);
      int m = (kt << 4) + ((lane >> 5) << 3);
      const float* src = (m < 256)
          ? J.whh + (size_t)wrow * 512 + (kh << 8) + m
          : J.wih + (size_t)wrow * KX + kh * (KX >> 1) + (m - 256);
      union { uint16_t h[8]; ulonglong2 v; } tmp;
#pragma unroll
      for (int j = 0; j < 8; ++j) tmp.h[j] = f2bf(src[j]);
      *(ulonglong2*)(Wl + (size_t)f * 8) = tmp.v;
    }
  }

  // FC assignment: dec0 WGs with u<8; wave wv owns out tile (ftr, ftc)
  const int isfc = (J.fcw != nullptr) && (u < 8);
  const int wgti = bg * 8 + u;             // 0..15
  const int ftc = wgti & 7;
  const int ftr = 2 * wv + (wgti >> 3);    // 0..7
  const int fcol = ftc * 16 + (ln & 15);
  const int farow = ftr * 16 + (ln & 15);
  float fbv = 0.0f;
  if (isfc) {
    fbv = J.fcb[fcol];
    for (int f = tid; f < 1024; f += 256) {
      int lane = f & 63, kt = f >> 6;
      int row = ftc * 16 + (lane & 15);
      int k = (kt << 5) + ((lane >> 4) << 3);
      const float* src = J.fcw + (size_t)row * 512 + k;
      union { uint16_t h[8]; ulonglong2 v; } tmp;
#pragma unroll
      for (int j = 0; j < 8; ++j) tmp.h[j] = f2bf(src[j]);
      *(ulonglong2*)(Wl + 32768 + (size_t)f * 8) = tmp.v;
    }
  }

  // ---- per-thread epilogue assignment: 2 hidden units ----
  const int rl = tid >> 2, ul2 = (tid & 3) * 2, bE = b0 + rl;
  const int hu = u * 8 + ul2;  // original hidden-unit index (pair base)
  const float Bi0 = J.bih[hu] + J.bhh[hu];
  const float Bi1 = J.bih[hu + 1] + J.bhh[hu + 1];
  const float Bf0 = J.bih[512 + hu] + J.bhh[512 + hu];
  const float Bf1 = J.bih[513 + hu] + J.bhh[513 + hu];
  const float Bg0 = J.bih[1024 + hu] + J.bhh[1024 + hu];
  const float Bg1 = J.bih[1025 + hu] + J.bhh[1025 + hu];
  const float Bo0 = J.bih[1536 + hu] + J.bhh[1536 + hu];
  const float Bo1 = J.bih[1537 + hu] + J.bhh[1537 + hu];
  {
    float c0v = 0.f, c1v = 0.f;
    if (J.c0) {
      c0v = J.c0[(size_t)bE * 512 + hu];
      c1v = J.c0[(size_t)bE * 512 + hu + 1];
    }
    cst[rl][ul2] = c0v;
    cst[rl][ul2 + 1] = c1v;
  }
  __syncthreads();

  const int mt = wv & 1, kh = wv >> 1;
  const int arow = b0 + mt * 32 + (ln & 31);
  const size_t hbase = (size_t)arow * 512 + (size_t)kh * 256 + ((ln >> 5) << 3);
  const uint16_t* wlh = Wl + (size_t)kh * HS + (size_t)ln * 8;
  const uint16_t* wlx = wlh + 16 * 512;
  const size_t hwr = (size_t)bE * 512 + hu;
  (void)hwr;
  const int tsteps = J.tsteps;
  const uint32_t FB = J.fb;

  for (int t = 0; t < tsteps; ++t) {
    f32x16 acc, acc2;
#pragma unroll
    for (int r = 0; r < 16; ++r) { acc[r] = 0.0f; acc2[r] = 0.0f; }

    // ---- x-part from global fp32 (enc0/dec0): no cross-WG dep -> pre-wait
    if (t < 512 && J.xring == nullptr) {
      const int tx = t - J.shift;
      if (tx >= 0) {
        const float* xb = J.xf + (size_t)arow * (512 * (size_t)KX) +
                          (size_t)tx * KX + kh * (KX >> 1) + ((ln >> 5) << 3);
        for (int kt = 0; kt < NTX; ++kt) {
          bf16x8 af = cvt8(xb + kt * 16);
          acc = MFMA32(af, *(const bf16x8*)(wlx + kt * 512), acc);
        }
      }
    }

    // ---- cross-WG flag waits: wave 0, one flag per lane, parallel poll ----
    // w_own : peers' h(t-1) stored              (flags >= FB+t)
    // w_prod: prev layer's h(t) in its ring     (flags >= FB+t+1)
    // w_cons: next layer done step t-8 so plane (t+1)&7 is free (>= FB+t-7)
    // w_fc  : dec1 h(t-4) stored, both groups   (flags >= FB+t-3)
    if (wv == 0) {
      const uint32_t* po = J.fown + bg * 64;
      const uint32_t* pp = J.fprod ? J.fprod + bg * 64 : nullptr;
      const uint32_t* pc = J.fcons ? J.fcons + bg * 64 : nullptr;
      const uint32_t* pf = J.fcons;  // FC: both groups
      const int w_own  = (t >= 1) && (t < 512);
      const int w_prod = (pp != nullptr) && (t < 512);
      const int w_cons = (pc != nullptr) && (t >= 8) && (t < 512);
      const int w_fc   = isfc && (t >= 4);
      if (w_own | w_prod | w_cons | w_fc) {
        const uint32_t to  = FB + (uint32_t)t;
        const uint32_t tp  = to + 1u;
        const uint32_t tcn = to - 7u;
        const uint32_t tfc = to - 3u;
        while (1) {
          int ok = 1;
          if (w_own)  ok &= (aldf(po + ln) >= to);
          if (w_prod) ok &= (aldf(pp + ln) >= tp);
          if (w_cons) ok &= (aldf(pc + ln) >= tcn);
          if (w_fc) {
            ok &= (aldf(pf + ln) >= tfc);
            ok &= (aldf(pf + 64 + ln) >= tfc);
          }
          if (__all(ok)) break;
          __builtin_amdgcn_s_sleep(1);
        }
      }
    }
    __syncthreads();

    if (t < 512) {
      // h-part: K 256 per half, self 8-plane ring, 16B coherent loads.
      // xring branch: counted vmcnt(16) -> MFMA ah while ax in flight.
      const uint16_t* hb = J.hring + (size_t)(t & 7) * 65536 + hbase;
      bf16x8 ah[16];
#pragma unroll
      for (int kt = 0; kt < 16; ++kt) ldg16(ah[kt], hb + kt * 16);
      if (J.xring) {  // previous layer's h(t), plane (t+1)&7 of ITS ring
        const uint16_t* xb = J.xring + (size_t)((t + 1) & 7) * 65536 + hbase;
        bf16x8 ax[16];
#pragma unroll
        for (int kt = 0; kt < 16; ++kt) ldg16(ax[kt], xb + kt * 16);
        VMCNT16(); SCHEDB();  // ah complete (vmcnt retires in issue order)
#pragma unroll
        for (int kt = 0; kt < 16; ++kt) {
          bf16x8 bw = *(const bf16x8*)(wlh + kt * 512);
          if (kt & 1) acc2 = MFMA32(ah[kt], bw, acc2);
          else        acc  = MFMA32(ah[kt], bw, acc);
        }
        VMCNT0(); SCHEDB();   // ax complete
#pragma unroll
        for (int kt = 0; kt < 16; ++kt) {
          bf16x8 bw = *(const bf16x8*)(wlx + kt * 512);
          if (kt & 1) acc2 = MFMA32(ax[kt], bw, acc2);
          else        acc  = MFMA32(ax[kt], bw, acc);
        }
      } else {
        VMCNT0(); SCHEDB();
#pragma unroll
        for (int kt = 0; kt < 16; ++kt) {
          bf16x8 bw = *(const bf16x8*)(wlh + kt * 512);
          if (kt & 1) acc2 = MFMA32(ah[kt], bw, acc2);
          else        acc  = MFMA32(ah[kt], bw, acc);
        }
      }
#pragma unroll
      for (int r = 0; r < 16; ++r) {
        int crow = (r & 3) + 8 * (r >> 2) + 4 * (ln >> 5);
        gb[kh][mt * 32 + crow][ln & 31] = acc[r] + acc2[r];
      }
      __syncthreads();

      // ---- epilogue: 2 hidden units per thread; stage h slice in LDS ----
      float i0 = sigm(gb[0][rl][ul2]      + gb[1][rl][ul2]      + Bi0);
      float i1 = sigm(gb[0][rl][ul2 + 1]  + gb[1][rl][ul2 + 1]  + Bi1);
      float f0 = sigm(gb[0][rl][8 + ul2]  + gb[1][rl][8 + ul2]  + Bf0);
      float f1 = sigm(gb[0][rl][9 + ul2]  + gb[1][rl][9 + ul2]  + Bf1);
      float g0 = tanh_f(gb[0][rl][16 + ul2] + gb[1][rl][16 + ul2] + Bg0);
      float g1 = tanh_f(gb[0][rl][17 + ul2] + gb[1][rl][17 + ul2] + Bg1);
      float o0 = sigm(gb[0][rl][24 + ul2] + gb[1][rl][24 + ul2] + Bo0);
      float o1 = sigm(gb[0][rl][25 + ul2] + gb[1][rl][25 + ul2] + Bo1);
      float cc0 = f0 * cst[rl][ul2]     + i0 * g0;
      float cc1 = f1 * cst[rl][ul2 + 1] + i1 * g1;
      cst[rl][ul2] = cc0;
      cst[rl][ul2 + 1] = cc1;
      float h0 = o0 * tanh_f(cc0);
      float h1 = o1 * tanh_f(cc1);
      hst[rl][ul2 >> 1] = (uint32_t)f2bf(h0) | ((uint32_t)f2bf(h1) << 16);

      __syncthreads();  // hst ready for wave0

      // ---- wave0 alone: 64 x 16B coherent stores -> drain -> flag ----
      if (wv == 0) {
        u32x4 hv4;
#pragma unroll
        for (int q = 0; q < 4; ++q) hv4[q] = hst[ln][q];
        uint16_t* dst = J.hring + (size_t)((t + 1) & 7) * 65536 +
                        (size_t)(b0 + ln) * 512 + (size_t)(u << 3);
        stg16(dst, hv4);
        VMCNT0();
        if (ln == 0)
          __hip_atomic_store(J.fown + bg * 64 + u, FB + (uint32_t)(t + 1),
                             __ATOMIC_RELAXED, __HIP_MEMORY_SCOPE_AGENT);
      }
    }

    // ---- fused FC head: out[:, t-4] = dec1_h(t-4) @ fcW^T + fcb (fp32) ----
    if (isfc && t >= 4) {
      const int tf = t - 4;
      const uint16_t* ha = J.fchr + (size_t)((tf + 1) & 7) * 65536 +
                           (size_t)farow * 512 + ((ln >> 4) << 3);
      const uint16_t* wb = Wl + 32768 + (size_t)ln * 8;
      bf16x8 af[16];
#pragma unroll
      for (int kt = 0; kt < 16; ++kt) ldg16(af[kt], ha + kt * 32);
      VMCNT0(); SCHEDB();
      f32x4 fa;
      fa[0] = fa[1] = fa[2] = fa[3] = 0.0f;
#pragma unroll
      for (int kt = 0; kt < 16; ++kt)
        fa = MFMA16(af[kt], *(const bf16x8*)(wb + kt * 512), fa);
#pragma unroll
      for (int r = 0; r < 4; ++r) {
        int row = ftr * 16 + ((ln >> 4) << 2) + r;  // batch index
        J.out[((size_t)row * 512 + tf) * 128 + fcol] = fa[r] + fbv;
      }
    }
  }
}

// ---------------- host launch ----------------
extern "C" void kernel_launch(void* const* d_in, const int* in_sizes, int n_in,
                              void* d_out, int out_size, void* d_ws, size_t ws_size,
                              hipStream_t stream) {
  (void)in_sizes; (void)n_in; (void)out_size; (void)ws_size;
  uint8_t* ws = (uint8_t*)d_ws;
  const float* x     = (const float*)d_in[0];
  const float* c_dec = (const float*)d_in[1];
  const float* W[16];
  for (int i = 0; i < 16; ++i) W[i] = (const float*)d_in[2 + i];
  // layer order in d_in: enc0{wih,whh,bih,bhh} enc1{...} dec0{...} dec1{...}
  const float* fcW = (const float*)d_in[18];
  const float* fcb = (const float*)d_in[19];

  uint32_t* FLG = (uint32_t*)(ws + OFF_FLG);
  uint16_t* HB0 = (uint16_t*)(ws + OFF_HB0);
  uint16_t* HB1 = (uint16_t*)(ws + OFF_HB1);
  // flag arrays: [2][64] for layer0 (enc0/dec0), [2][64] for layer1
  uint32_t* FL0 = FLG + 0;    // L0: bg0 [0..63], bg1 [64..127]
  uint32_t* FL1 = FLG + 128;  // L1: bg0 [0..63], bg1 [64..127]

  // 1) zero flags + h-ring plane0 (h_{-1} = 0), write-through
  hipLaunchKernelGGL(init_kernel, dim3(128), dim3(256), 0, stream,
                     FLG, (uint32_t*)HB0, (uint32_t*)HB1);

  // 2) phase A: enc0 (x -> HB0) || enc1 (HB0 -> HB1; seq discarded)
  {
    PJob a; a.whh = W[1]; a.wih = W[0]; a.bih = W[2]; a.bhh = W[3];
    a.xf = x; a.xring = nullptr; a.hring = HB0; a.c0 = nullptr;
    a.fown = FL0; a.fprod = nullptr; a.fcons = FL1;
    a.fcw = nullptr; a.fcb = nullptr; a.fchr = nullptr; a.out = nullptr;
    a.KX = 128; a.shift = 0; a.tsteps = 512; a.fb = 0;
    PJob b; b.whh = W[5]; b.wih = W[4]; b.bih = W[6]; b.bhh = W[7];
    b.xf = nullptr; b.xring = HB0; b.hring = HB1; b.c0 = nullptr;
    b.fown = FL1; b.fprod = FL0; b.fcons = nullptr;
    b.fcw = nullptr; b.fcb = nullptr; b.fchr = nullptr; b.out = nullptr;
    b.KX = 512; b.shift = 0; b.tsteps = 512; b.fb = 0;
    void* args[2] = { &a, &b };
    (void)hipLaunchCooperativeKernel((const void*)lstm_pipe, dim3(256), dim3(256), args, 0, stream);
  }

  // 3) phase B: dec0 (shift(x) -> HB0, h0 = enc0 hT in HB0 plane0, c0=c_dec[0],
  //    + fused FC from dec1's ring) || dec1 (HB0 -> HB1, h0 = enc1 hT, c0=c_dec[1])
  //    Flag arrays reused with fb=512 (phase A leaves every flag at exactly 512;
  //    512 % 8 == 0 so the h_T handoff lands in plane 0 of each ring).
  {
    PJob a; a.whh = W[9]; a.wih = W[8]; a.bih = W[10]; a.bhh = W[11];
    a.xf = x; a.xring = nullptr; a.hring = HB0; a.c0 = c_dec;
    a.fown = FL0; a.fprod = nullptr; a.fcons = FL1;
    a.fcw = fcW; a.fcb = fcb; a.fchr = HB1; a.out = (float*)d_out;
    a.KX = 128; a.shift = 1; a.tsteps = 516; a.fb = 512;
    PJob b; b.whh = W[13]; b.wih = W[12]; b.bih = W[14]; b.bhh = W[15];
    b.xf = nullptr; b.xring = HB0; b.hring = HB1; b.c0 = c_dec + 65536;
    b.fown = FL1; b.fprod = FL0; b.fcons = nullptr;
    b.fcw = nullptr; b.fcb = nullptr; b.fchr = nullptr; b.out = nullptr;
    b.KX = 512; b.shift = 0; b.tsteps = 512; b.fb = 512;
    void* args[2] = { &a, &b };
    (void)hipLaunchCooperativeKernel((const void*)lstm_pipe, dim3(256), dim3(256), args, 0, stream);
  }
}